// Round 2
// baseline (438.734 us; speedup 1.0000x reference)
//
#include <hip/hip_runtime.h>
#include <cstdint>

#define E_EXP 8
#define BATCH 8192
#define D0 480
#define D1 512
#define D2 512
#define D3 363
#define K1 (E_EXP * D0)  // 3840
#define K2 (E_EXP * D1)  // 4096
#define K3 (E_EXP * D2)  // 4096
#define N3PAD 384

typedef _Float16 f16x8 __attribute__((ext_vector_type(8)));
typedef float f32x4 __attribute__((ext_vector_type(4)));
typedef unsigned short u16;

// fp32 -> fp16 bits (RTN)
__device__ __forceinline__ u16 f2h(float f) {
    _Float16 h = (_Float16)f;
    return __builtin_bit_cast(u16, h);
}

// async global->LDS, 16B per lane; LDS dest = wave-uniform base + lane*16
__device__ __forceinline__ void async16(const u16* g, u16* s) {
    __builtin_amdgcn_global_load_lds(
        reinterpret_cast<const __attribute__((address_space(1))) void*>(
            reinterpret_cast<uintptr_t>(g)),
        reinterpret_cast<__attribute__((address_space(3))) void*>(
            reinterpret_cast<uintptr_t>(s)),
        16, 0, 0);
}

// W[e,o,i] fp32 -> Wflat[o, e*IN+i] fp16, rows padded with zeros to NPAD
__global__ void pack_weights(const float* __restrict__ src, u16* __restrict__ dst,
                             int OUT, int IN, int K, int NPAD) {
    int total = NPAD * (K >> 2);
    for (int idx = blockIdx.x * blockDim.x + threadIdx.x; idx < total;
         idx += gridDim.x * blockDim.x) {
        int m4 = idx << 2;
        int o = m4 / K;
        int rem = m4 - o * K;
        int e = rem / IN;
        int i = rem - e * IN;
        ushort4 w;
        if (o < OUT) {
            const float4 v = *reinterpret_cast<const float4*>(
                src + (size_t)(e * OUT + o) * IN + i);
            w.x = f2h(v.x); w.y = f2h(v.y); w.z = f2h(v.z); w.w = f2h(v.w);
        } else {
            w.x = 0; w.y = 0; w.z = 0; w.w = 0;
        }
        *reinterpret_cast<ushort4*>(dst + (size_t)m4) = w;
    }
}

// Aaug[b, e*IN+i] = fp16(blend[e,b] * act[b,i]); one block per row b
__global__ void build_aug(const float* __restrict__ act, const float* __restrict__ blend,
                          u16* __restrict__ dst, int IN, int K) {
    int b = blockIdx.x;
    float bl[E_EXP];
#pragma unroll
    for (int e = 0; e < E_EXP; ++e) bl[e] = blend[e * BATCH + b];
    const float* arow = act + (size_t)b * IN;
    u16* drow = dst + (size_t)b * K;
    int chunks = K >> 2;
    for (int c = threadIdx.x; c < chunks; c += blockDim.x) {
        int m4 = c << 2;
        int e = m4 / IN;
        int i = m4 - e * IN;
        float4 v = *reinterpret_cast<const float4*>(arow + i);
        float s = bl[e];
        ushort4 w;
        w.x = f2h(v.x * s); w.y = f2h(v.y * s);
        w.z = f2h(v.z * s); w.w = f2h(v.w * s);
        *reinterpret_cast<ushort4*>(drow + m4) = w;
    }
}

// C[m,n] = sum_k A[m,k]*Bt[n,k]  (+ blended bias, +ELU for mode 0)
// 128x128 tile, BK=64, 512 threads = 8 waves (2 m x 4 n), wave tile 64x32
__global__ __launch_bounds__(512, 2) void gemm_bt(
    const u16* __restrict__ A, const u16* __restrict__ Bt,
    const float* __restrict__ blend, const float* __restrict__ bias,
    float* __restrict__ out, int K, int OUT, int mode) {
    __shared__ __align__(16) u16 As[128 * 64];
    __shared__ __align__(16) u16 Bs[128 * 64];
    const int tid = threadIdx.x;
    const int w = tid >> 6;
    const int lane = tid & 63;
    const int wm = w & 1, wn = w >> 1;
    const int q = lane >> 4, l15 = lane & 15;
    const int bm = blockIdx.y, bn = blockIdx.x;

    f32x4 acc[4][2];
#pragma unroll
    for (int mi = 0; mi < 4; ++mi)
#pragma unroll
        for (int ni = 0; ni < 2; ++ni) acc[mi][ni] = (f32x4){0.f, 0.f, 0.f, 0.f};

    // staging: tile = 16 chunks of 1KB; wave w handles chunks {w, w+8}
    const int mrow = w * 8 + (lane >> 3);  // row in tile (r=0 half)
    const int c8 = (lane & 7) << 3;        // k-offset in elems
    const u16* gA = A + (size_t)(bm * 128 + mrow) * K + c8;
    const u16* gB = Bt + (size_t)(bn * 128 + mrow) * K + c8;
    u16* sA = &As[w * 512];
    u16* sB = &Bs[w * 512];
    const size_t rstep = (size_t)64 * K;

    const int nk = K >> 6;
    for (int kt = 0; kt < nk; ++kt) {
        async16(gA, sA);
        async16(gA + rstep, sA + 4096);
        async16(gB, sB);
        async16(gB + rstep, sB + 4096);
        gA += 64; gB += 64;
        __syncthreads();
#pragma unroll
        for (int ks = 0; ks < 2; ++ks) {
            f16x8 af[4], bfr[2];
#pragma unroll
            for (int mi = 0; mi < 4; ++mi)
                af[mi] = *reinterpret_cast<const f16x8*>(
                    &As[(wm * 64 + mi * 16 + l15) * 64 + ks * 32 + q * 8]);
#pragma unroll
            for (int ni = 0; ni < 2; ++ni)
                bfr[ni] = *reinterpret_cast<const f16x8*>(
                    &Bs[(wn * 32 + ni * 16 + l15) * 64 + ks * 32 + q * 8]);
#pragma unroll
            for (int mi = 0; mi < 4; ++mi)
#pragma unroll
                for (int ni = 0; ni < 2; ++ni)
                    acc[mi][ni] = __builtin_amdgcn_mfma_f32_16x16x32_f16(
                        af[mi], bfr[ni], acc[mi][ni], 0, 0, 0);
        }
        __syncthreads();
    }

    // epilogue: blended bias from LDS-staged blend/bias tiles
    float* Bl = reinterpret_cast<float*>(As);  // [128][8] blend[e, bm*128+r]
    float* Bi = reinterpret_cast<float*>(Bs);  // [128][8] bias[e, bn*128+c]
    for (int idx = tid; idx < 1024; idx += 512) {
        int e = idx >> 7, r = idx & 127;
        Bl[r * 8 + e] = blend[e * BATCH + bm * 128 + r];
        int cg = bn * 128 + r;
        Bi[r * 8 + e] = (cg < OUT) ? bias[e * OUT + cg] : 0.f;
    }
    __syncthreads();
#pragma unroll
    for (int mi = 0; mi < 4; ++mi) {
#pragma unroll
        for (int ni = 0; ni < 2; ++ni) {
            int col_l = wn * 32 + ni * 16 + l15;
            int gcol = bn * 128 + col_l;
#pragma unroll
            for (int r = 0; r < 4; ++r) {
                int rl = wm * 64 + mi * 16 + q * 4 + r;
                float bb = 0.f;
#pragma unroll
                for (int e = 0; e < E_EXP; ++e) bb += Bl[rl * 8 + e] * Bi[col_l * 8 + e];
                float v = acc[mi][ni][r] + bb;
                size_t off = (size_t)(bm * 128 + rl) * OUT + gcol;
                if (mode == 0) {
                    out[off] = v > 0.f ? v : expm1f(v);  // ELU
                } else if (gcol < OUT) {
                    out[off] = v;  // raw logits
                }
            }
        }
    }
}

// in-place row softmax over D3=363 cols; 128 threads (2 waves) per row
__global__ void softmax_rows(float* __restrict__ out) {
    const int b = blockIdx.x;
    float* row = out + (size_t)b * D3;
    const int tid = threadIdx.x;
    const int lane = tid & 63, w = tid >> 6;
    float v[3];
    float mx = -3.4e38f;
    int n = 0;
    for (int i = tid; i < D3; i += 128) { v[n] = row[i]; mx = fmaxf(mx, v[n]); ++n; }
#pragma unroll
    for (int off = 32; off >= 1; off >>= 1) mx = fmaxf(mx, __shfl_xor(mx, off, 64));
    __shared__ float sm[4];
    if (lane == 0) sm[w] = mx;
    __syncthreads();
    mx = fmaxf(sm[0], sm[1]);
    float s = 0.f;
    for (int j = 0; j < n; ++j) { v[j] = expf(v[j] - mx); s += v[j]; }
#pragma unroll
    for (int off = 32; off >= 1; off >>= 1) s += __shfl_xor(s, off, 64);
    if (lane == 0) sm[2 + w] = s;
    __syncthreads();
    float inv = 1.f / (sm[2] + sm[3]);
    n = 0;
    for (int i = tid; i < D3; i += 128) { row[i] = v[n] * inv; ++n; }
}

extern "C" void kernel_launch(void* const* d_in, const int* in_sizes, int n_in,
                              void* d_out, int out_size, void* d_ws, size_t ws_size,
                              hipStream_t stream) {
    const float* x = (const float*)d_in[0];
    const float* blend = (const float*)d_in[1];
    const float* W1 = (const float*)d_in[2];
    const float* b1 = (const float*)d_in[3];
    const float* W2 = (const float*)d_in[4];
    const float* b2 = (const float*)d_in[5];
    const float* W3 = (const float*)d_in[6];
    const float* b3 = (const float*)d_in[7];
    float* outp = (float*)d_out;

    char* ws = (char*)d_ws;
    u16* wf1 = (u16*)ws;  ws += (size_t)512 * K1 * 2;     // 3.93 MB
    u16* wf2 = (u16*)ws;  ws += (size_t)512 * K2 * 2;     // 4.19 MB
    u16* wf3 = (u16*)ws;  ws += (size_t)N3PAD * K3 * 2;   // 3.15 MB
    u16* augA = (u16*)ws; ws += (size_t)BATCH * K2 * 2;   // 67.1 MB
    u16* augB = (u16*)ws; ws += (size_t)BATCH * K2 * 2;   // 67.1 MB
    float* hbuf = (float*)ws;                             // 16.8 MB

    pack_weights<<<1024, 256, 0, stream>>>(W1, wf1, 512, D0, K1, 512);
    pack_weights<<<1024, 256, 0, stream>>>(W2, wf2, 512, D1, K2, 512);
    pack_weights<<<1024, 256, 0, stream>>>(W3, wf3, D3, D2, K3, N3PAD);

    build_aug<<<BATCH, 256, 0, stream>>>(x, blend, augA, D0, K1);
    gemm_bt<<<dim3(4, 64), 512, 0, stream>>>(augA, wf1, blend, b1, hbuf, K1, 512, 0);
    build_aug<<<BATCH, 256, 0, stream>>>(hbuf, blend, augB, D1, K2);
    gemm_bt<<<dim3(4, 64), 512, 0, stream>>>(augB, wf2, blend, b2, hbuf, K2, 512, 0);
    build_aug<<<BATCH, 256, 0, stream>>>(hbuf, blend, augA, D2, K3);
    gemm_bt<<<dim3(3, 64), 512, 0, stream>>>(augA, wf3, blend, b3, outp, K3, D3, 1);
    softmax_rows<<<BATCH, 128, 0, stream>>>(outp);
}

// Round 3
// 294.410 us; speedup vs baseline: 1.4902x; 1.4902x over previous
//
#include <hip/hip_runtime.h>
#include <cstdint>

#define E_EXP 8
#define BATCH 8192
#define D0 480
#define D1 512
#define D2 512
#define D3 363
#define K1 (E_EXP * D0)  // 3840
#define K2 (E_EXP * D1)  // 4096
#define K3 (E_EXP * D2)  // 4096
#define N3PAD 384
#define SPLIT 4

typedef _Float16 f16x8 __attribute__((ext_vector_type(8)));
typedef float f32x4 __attribute__((ext_vector_type(4)));
typedef unsigned short u16;
typedef u16 u16x8 __attribute__((ext_vector_type(8)));

__device__ __forceinline__ u16 f2h(float f) {
    _Float16 h = (_Float16)f;
    return __builtin_bit_cast(u16, h);
}

// async global->LDS, 16B per lane; LDS dest = wave-uniform base + lane*16
__device__ __forceinline__ void async16(const u16* g, u16* s) {
    __builtin_amdgcn_global_load_lds(
        reinterpret_cast<const __attribute__((address_space(1))) void*>(
            reinterpret_cast<uintptr_t>(g)),
        reinterpret_cast<__attribute__((address_space(3))) void*>(
            reinterpret_cast<uintptr_t>(s)),
        16, 0, 0);
}

// W[e,o,i] fp32 -> Wflat[o, e*IN+i] fp16, rows padded with zeros to NPAD
__global__ void pack_weights(const float* __restrict__ src, u16* __restrict__ dst,
                             int OUT, int IN, int K, int NPAD) {
    int total = NPAD * (K >> 2);
    for (int idx = blockIdx.x * blockDim.x + threadIdx.x; idx < total;
         idx += gridDim.x * blockDim.x) {
        int m4 = idx << 2;
        int o = m4 / K;
        int rem = m4 - o * K;
        int e = rem / IN;
        int i = rem - e * IN;
        ushort4 w;
        if (o < OUT) {
            const float4 v = *reinterpret_cast<const float4*>(
                src + (size_t)(e * OUT + o) * IN + i);
            w.x = f2h(v.x); w.y = f2h(v.y); w.z = f2h(v.z); w.w = f2h(v.w);
        } else {
            w.x = 0; w.y = 0; w.z = 0; w.w = 0;
        }
        *reinterpret_cast<ushort4*>(dst + (size_t)m4) = w;
    }
}

// Layer-1 only: Aaug[b, e*IN+i] = fp16(blend[e,b] * x[b,i])
__global__ void build_aug(const float* __restrict__ act, const float* __restrict__ blend,
                          u16* __restrict__ dst, int IN, int K) {
    int b = blockIdx.x;
    float bl[E_EXP];
#pragma unroll
    for (int e = 0; e < E_EXP; ++e) bl[e] = blend[e * BATCH + b];
    const float* arow = act + (size_t)b * IN;
    u16* drow = dst + (size_t)b * K;
    int chunks = K >> 2;
    for (int c = threadIdx.x; c < chunks; c += blockDim.x) {
        int m4 = c << 2;
        int e = m4 / IN;
        int i = m4 - e * IN;
        float4 v = *reinterpret_cast<const float4*>(arow + i);
        float s = bl[e];
        ushort4 w;
        w.x = f2h(v.x * s); w.y = f2h(v.y * s);
        w.z = f2h(v.z * s); w.w = f2h(v.w * s);
        *reinterpret_cast<ushort4*>(drow + m4) = w;
    }
}

// Split-K GEMM: P[s][m][n] = sum_{k in split s} A[m,k]*Bt[n,k]
// 128x128 tile, BK=64, 512 threads = 8 waves (2m x 4n), XOR-swizzled LDS.
// Grid 1D = 64*nbn*SPLIT, XCD-swizzled so all (bn,s) sharing bm land on one XCD.
__global__ __launch_bounds__(512, 8) void gemm_splitk(
    const u16* __restrict__ A, const u16* __restrict__ Bt,
    float* __restrict__ P, int K, int Ks, int NP, int nbn) {
    __shared__ __align__(16) u16 As[128 * 64];
    __shared__ __align__(16) u16 Bs[128 * 64];
    const int tid = threadIdx.x;
    const int w = tid >> 6;
    const int lane = tid & 63;
    const int wm = w & 1, wn = w >> 1;
    const int q = lane >> 4, l15 = lane & 15;

    // XCD-aware decode: bm keyed to (id & 7) so A-slab sharers colocate
    const int id = blockIdx.x;
    const int xcd = id & 7;
    const int j = id >> 3;
    const int bm = (j & 7) * 8 + xcd;
    const int rest = j >> 3;
    const int bn = rest % nbn;
    const int sp = rest / nbn;

    f32x4 acc[4][2];
#pragma unroll
    for (int mi = 0; mi < 4; ++mi)
#pragma unroll
        for (int ni = 0; ni < 2; ++ni) acc[mi][ni] = (f32x4){0.f, 0.f, 0.f, 0.f};

    // staging: wave w stages rows {w*8..w*8+7} and {+64}; XOR-swizzled k source
    const int l8 = lane & 7, h8 = lane >> 3;
    const int mrow = w * 8 + h8;
    const int c8 = ((l8 ^ h8) << 3);  // swizzled k-offset (elems)
    const u16* gA = A + (size_t)(bm * 128 + mrow) * K + (size_t)sp * Ks + c8;
    const u16* gB = Bt + (size_t)(bn * 128 + mrow) * K + (size_t)sp * Ks + c8;
    u16* sA = &As[w * 512];
    u16* sB = &Bs[w * 512];
    const size_t rstep = (size_t)64 * K;

    // fragment read column base (swizzled): slot = (ks*4+q) ^ (r&7), r&7 == l15&7
    const int colsw = ((q ^ (l15 & 7)) << 3);

    const int nk = Ks >> 6;
    for (int kt = 0; kt < nk; ++kt) {
        async16(gA, sA);
        async16(gA + rstep, sA + 4096);
        async16(gB, sB);
        async16(gB + rstep, sB + 4096);
        gA += 64; gB += 64;
        __syncthreads();
#pragma unroll
        for (int ks = 0; ks < 2; ++ks) {
            f16x8 af[4], bfr[2];
#pragma unroll
            for (int mi = 0; mi < 4; ++mi)
                af[mi] = *reinterpret_cast<const f16x8*>(
                    &As[(wm * 64 + mi * 16 + l15) * 64 + (colsw ^ (ks << 5))]);
#pragma unroll
            for (int ni = 0; ni < 2; ++ni)
                bfr[ni] = *reinterpret_cast<const f16x8*>(
                    &Bs[(wn * 32 + ni * 16 + l15) * 64 + (colsw ^ (ks << 5))]);
#pragma unroll
            for (int mi = 0; mi < 4; ++mi)
#pragma unroll
                for (int ni = 0; ni < 2; ++ni)
                    acc[mi][ni] = __builtin_amdgcn_mfma_f32_16x16x32_f16(
                        af[mi], bfr[ni], acc[mi][ni], 0, 0, 0);
        }
        __syncthreads();
    }

    // write fp32 partials (no bias/activation here)
#pragma unroll
    for (int mi = 0; mi < 4; ++mi) {
#pragma unroll
        for (int ni = 0; ni < 2; ++ni) {
            int gcol = bn * 128 + wn * 32 + ni * 16 + l15;
#pragma unroll
            for (int r = 0; r < 4; ++r) {
                int rl = wm * 64 + mi * 16 + q * 4 + r;
                P[((size_t)sp * BATCH + bm * 128 + rl) * NP + gcol] = acc[mi][ni][r];
            }
        }
    }
}

// P partial-sum + blended bias + ELU + write next-layer aug (fp16, stride K2).
// One wave per row; 4 rows per block.
__global__ __launch_bounds__(256) void reduce_aug(
    const float* __restrict__ P, const float* __restrict__ blend,
    const float* __restrict__ bias, u16* __restrict__ aug) {
    const int w = threadIdx.x >> 6, lane = threadIdx.x & 63;
    const int b = blockIdx.x * 4 + w;
    const int o0 = lane << 3;
    float v[8];
#pragma unroll
    for (int j = 0; j < 8; ++j) v[j] = 0.f;
#pragma unroll
    for (int s = 0; s < SPLIT; ++s) {
        const float* p = P + ((size_t)s * BATCH + b) * 512 + o0;
        float4 a = *reinterpret_cast<const float4*>(p);
        float4 c = *reinterpret_cast<const float4*>(p + 4);
        v[0] += a.x; v[1] += a.y; v[2] += a.z; v[3] += a.w;
        v[4] += c.x; v[5] += c.y; v[6] += c.z; v[7] += c.w;
    }
    float bl[E_EXP];
#pragma unroll
    for (int e = 0; e < E_EXP; ++e) bl[e] = blend[e * BATCH + b];
#pragma unroll
    for (int e = 0; e < E_EXP; ++e) {
        const float* bp = bias + e * 512 + o0;
        float4 a = *reinterpret_cast<const float4*>(bp);
        float4 c = *reinterpret_cast<const float4*>(bp + 4);
        float s = bl[e];
        v[0] += s * a.x; v[1] += s * a.y; v[2] += s * a.z; v[3] += s * a.w;
        v[4] += s * c.x; v[5] += s * c.y; v[6] += s * c.z; v[7] += s * c.w;
    }
#pragma unroll
    for (int j = 0; j < 8; ++j) v[j] = v[j] > 0.f ? v[j] : expm1f(v[j]);
#pragma unroll
    for (int e = 0; e < E_EXP; ++e) {
        float s = bl[e];
        u16x8 o;
#pragma unroll
        for (int j = 0; j < 8; ++j) o[j] = f2h(s * v[j]);
        *reinterpret_cast<u16x8*>(aug + (size_t)b * K2 + e * 512 + o0) = o;
    }
}

// P partial-sum + blended bias + softmax -> out. 128 threads (2 waves) per row.
__global__ __launch_bounds__(128) void reduce_softmax(
    const float* __restrict__ P, const float* __restrict__ blend,
    const float* __restrict__ bias, float* __restrict__ out) {
    const int b = blockIdx.x;
    const int tid = threadIdx.x, lane = tid & 63, w = tid >> 6;
    float bl[E_EXP];
#pragma unroll
    for (int e = 0; e < E_EXP; ++e) bl[e] = blend[e * BATCH + b];
    float v[3];
    int n = 0;
    float mx = -3.4e38f;
    for (int i = tid; i < D3; i += 128) {
        float s = 0.f;
#pragma unroll
        for (int sp = 0; sp < SPLIT; ++sp)
            s += P[((size_t)sp * BATCH + b) * N3PAD + i];
#pragma unroll
        for (int e = 0; e < E_EXP; ++e) s += bl[e] * bias[e * D3 + i];
        v[n] = s; mx = fmaxf(mx, s); ++n;
    }
#pragma unroll
    for (int off = 32; off >= 1; off >>= 1) mx = fmaxf(mx, __shfl_xor(mx, off, 64));
    __shared__ float sm[4];
    if (lane == 0) sm[w] = mx;
    __syncthreads();
    mx = fmaxf(sm[0], sm[1]);
    float s = 0.f;
    for (int j = 0; j < n; ++j) { v[j] = expf(v[j] - mx); s += v[j]; }
#pragma unroll
    for (int off = 32; off >= 1; off >>= 1) s += __shfl_xor(s, off, 64);
    if (lane == 0) sm[2 + w] = s;
    __syncthreads();
    float inv = 1.f / (sm[2] + sm[3]);
    n = 0;
    for (int i = tid; i < D3; i += 128) { out[(size_t)b * D3 + i] = v[n] * inv; ++n; }
}

extern "C" void kernel_launch(void* const* d_in, const int* in_sizes, int n_in,
                              void* d_out, int out_size, void* d_ws, size_t ws_size,
                              hipStream_t stream) {
    const float* x = (const float*)d_in[0];
    const float* blend = (const float*)d_in[1];
    const float* W1 = (const float*)d_in[2];
    const float* b1 = (const float*)d_in[3];
    const float* W2 = (const float*)d_in[4];
    const float* b2 = (const float*)d_in[5];
    const float* W3 = (const float*)d_in[6];
    const float* b3 = (const float*)d_in[7];
    float* outp = (float*)d_out;

    char* ws = (char*)d_ws;
    u16* wf1 = (u16*)ws;  ws += (size_t)512 * K1 * 2;        // 3.93 MB
    u16* wf2 = (u16*)ws;  ws += (size_t)512 * K2 * 2;        // 4.19 MB
    u16* wf3 = (u16*)ws;  ws += (size_t)N3PAD * K3 * 2;      // 3.15 MB
    u16* aug = (u16*)ws;  ws += (size_t)BATCH * K2 * 2;      // 67.1 MB
    float* P = (float*)ws;                                   // 4*8192*512*4 = 67.1 MB

    pack_weights<<<1024, 256, 0, stream>>>(W1, wf1, 512, D0, K1, 512);
    pack_weights<<<1024, 256, 0, stream>>>(W2, wf2, 512, D1, K2, 512);
    pack_weights<<<1024, 256, 0, stream>>>(W3, wf3, D3, D2, K3, N3PAD);

    build_aug<<<BATCH, 256, 0, stream>>>(x, blend, aug, D0, K1);
    gemm_splitk<<<64 * 4 * SPLIT, 512, 0, stream>>>(aug, wf1, P, K1, K1 / SPLIT, 512, 4);
    reduce_aug<<<BATCH / 4, 256, 0, stream>>>(P, blend, b1, aug);
    gemm_splitk<<<64 * 4 * SPLIT, 512, 0, stream>>>(aug, wf2, P, K2, K2 / SPLIT, 512, 4);
    reduce_aug<<<BATCH / 4, 256, 0, stream>>>(P, blend, b2, aug);
    gemm_splitk<<<64 * 3 * SPLIT, 512, 0, stream>>>(aug, wf3, P, K3, K3 / SPLIT, N3PAD, 3);
    reduce_softmax<<<BATCH, 128, 0, stream>>>(P, blend, b3, outp);
}

// Round 4
// 271.757 us; speedup vs baseline: 1.6144x; 1.0834x over previous
//
#include <hip/hip_runtime.h>
#include <cstdint>

#define E_EXP 8
#define BATCH 8192
#define D0 480
#define D1 512
#define D2 512
#define D3 363
#define K1 (E_EXP * D0)  // 3840
#define K2 (E_EXP * D1)  // 4096
#define K3 (E_EXP * D2)  // 4096
#define N3PAD 384
#define SPLIT 2

typedef _Float16 f16x8 __attribute__((ext_vector_type(8)));
typedef float f32x4 __attribute__((ext_vector_type(4)));
typedef unsigned short u16;
typedef u16 u16x8 __attribute__((ext_vector_type(8)));

__device__ __forceinline__ u16 f2h(float f) {
    _Float16 h = (_Float16)f;
    return __builtin_bit_cast(u16, h);
}

// async global->LDS, 16B per lane; LDS dest = wave-uniform base + lane*16
__device__ __forceinline__ void async16(const u16* g, u16* s) {
    __builtin_amdgcn_global_load_lds(
        reinterpret_cast<const __attribute__((address_space(1))) void*>(
            reinterpret_cast<uintptr_t>(g)),
        reinterpret_cast<__attribute__((address_space(3))) void*>(
            reinterpret_cast<uintptr_t>(s)),
        16, 0, 0);
}

// W[e,o,i] fp32 -> Wflat[o, e*IN+i] fp16, rows zero-padded to NPAD
__device__ __forceinline__ void pack_seg(const float* __restrict__ src,
                                         u16* __restrict__ dst,
                                         int OUT, int IN, int K, int NPAD) {
    int total = NPAD * (K >> 2);
    for (int idx = blockIdx.x * blockDim.x + threadIdx.x; idx < total;
         idx += gridDim.x * blockDim.x) {
        int m4 = idx << 2;
        int o = m4 / K;
        int rem = m4 - o * K;
        int e = rem / IN;
        int i = rem - e * IN;
        ushort4 w;
        if (o < OUT) {
            const float4 v = *reinterpret_cast<const float4*>(
                src + (size_t)(e * OUT + o) * IN + i);
            w.x = f2h(v.x); w.y = f2h(v.y); w.z = f2h(v.z); w.w = f2h(v.w);
        } else {
            w.x = 0; w.y = 0; w.z = 0; w.w = 0;
        }
        *reinterpret_cast<ushort4*>(dst + (size_t)m4) = w;
    }
}

__global__ void pack_all(const float* __restrict__ W1, const float* __restrict__ W2,
                         const float* __restrict__ W3, u16* __restrict__ wf1,
                         u16* __restrict__ wf2, u16* __restrict__ wf3) {
    pack_seg(W1, wf1, 512, D0, K1, 512);
    pack_seg(W2, wf2, 512, D1, K2, 512);
    pack_seg(W3, wf3, D3, D2, K3, N3PAD);
}

// Layer-1 only: Aaug[b, e*IN+i] = fp16(blend[e,b] * x[b,i])
__global__ void build_aug(const float* __restrict__ act, const float* __restrict__ blend,
                          u16* __restrict__ dst, int IN, int K) {
    int b = blockIdx.x;
    float bl[E_EXP];
#pragma unroll
    for (int e = 0; e < E_EXP; ++e) bl[e] = blend[e * BATCH + b];
    const float* arow = act + (size_t)b * IN;
    u16* drow = dst + (size_t)b * K;
    int chunks = K >> 2;
    for (int c = threadIdx.x; c < chunks; c += blockDim.x) {
        int m4 = c << 2;
        int e = m4 / IN;
        int i = m4 - e * IN;
        float4 v = *reinterpret_cast<const float4*>(arow + i);
        float s = bl[e];
        ushort4 w;
        w.x = f2h(v.x * s); w.y = f2h(v.y * s);
        w.z = f2h(v.z * s); w.w = f2h(v.w * s);
        *reinterpret_cast<ushort4*>(drow + m4) = w;
    }
}

// Split-K GEMM: P[s][m][n] (fp16) = sum_{k in split s} A[m,k]*Bt[n,k]
// 128x128 tile, BK=64, 512 threads = 8 waves (2m x 4n), XOR-swizzled LDS.
__global__ __launch_bounds__(512, 8) void gemm_splitk(
    const u16* __restrict__ A, const u16* __restrict__ Bt,
    u16* __restrict__ P, int K, int Ks, int NP, int nbn) {
    __shared__ __align__(16) u16 As[128 * 64];
    __shared__ __align__(16) u16 Bs[128 * 64];
    const int tid = threadIdx.x;
    const int w = tid >> 6;
    const int lane = tid & 63;
    const int wm = w & 1, wn = w >> 1;
    const int q = lane >> 4, l15 = lane & 15;

    // XCD-aware decode: bm keyed to (id & 7) so A-slab sharers colocate
    const int id = blockIdx.x;
    const int xcd = id & 7;
    const int j = id >> 3;
    const int bm = (j & 7) * 8 + xcd;
    const int rest = j >> 3;
    const int bn = rest % nbn;
    const int sp = rest / nbn;

    f32x4 acc[4][2];
#pragma unroll
    for (int mi = 0; mi < 4; ++mi)
#pragma unroll
        for (int ni = 0; ni < 2; ++ni) acc[mi][ni] = (f32x4){0.f, 0.f, 0.f, 0.f};

    // staging: wave w stages rows {w*8..w*8+7} and {+64}; XOR-swizzled k source
    const int l8 = lane & 7, h8 = lane >> 3;
    const int mrow = w * 8 + h8;
    const int c8 = ((l8 ^ h8) << 3);  // swizzled k-offset (elems)
    const u16* gA = A + (size_t)(bm * 128 + mrow) * K + (size_t)sp * Ks + c8;
    const u16* gB = Bt + (size_t)(bn * 128 + mrow) * K + (size_t)sp * Ks + c8;
    u16* sA = &As[w * 512];
    u16* sB = &Bs[w * 512];
    const size_t rstep = (size_t)64 * K;

    // fragment read column base (swizzled): slot = (ks*4+q) ^ (r&7)
    const int colsw = ((q ^ (l15 & 7)) << 3);

    const int nk = Ks >> 6;
    for (int kt = 0; kt < nk; ++kt) {
        async16(gA, sA);
        async16(gA + rstep, sA + 4096);
        async16(gB, sB);
        async16(gB + rstep, sB + 4096);
        gA += 64; gB += 64;
        __syncthreads();
#pragma unroll
        for (int ks = 0; ks < 2; ++ks) {
            f16x8 af[4], bfr[2];
#pragma unroll
            for (int mi = 0; mi < 4; ++mi)
                af[mi] = *reinterpret_cast<const f16x8*>(
                    &As[(wm * 64 + mi * 16 + l15) * 64 + (colsw ^ (ks << 5))]);
#pragma unroll
            for (int ni = 0; ni < 2; ++ni)
                bfr[ni] = *reinterpret_cast<const f16x8*>(
                    &Bs[(wn * 32 + ni * 16 + l15) * 64 + (colsw ^ (ks << 5))]);
#pragma unroll
            for (int mi = 0; mi < 4; ++mi)
#pragma unroll
                for (int ni = 0; ni < 2; ++ni)
                    acc[mi][ni] = __builtin_amdgcn_mfma_f32_16x16x32_f16(
                        af[mi], bfr[ni], acc[mi][ni], 0, 0, 0);
        }
        __syncthreads();
    }

    // write fp16 partials
#pragma unroll
    for (int mi = 0; mi < 4; ++mi) {
#pragma unroll
        for (int ni = 0; ni < 2; ++ni) {
            int gcol = bn * 128 + wn * 32 + ni * 16 + l15;
#pragma unroll
            for (int r = 0; r < 4; ++r) {
                int rl = wm * 64 + mi * 16 + q * 4 + r;
                P[((size_t)sp * BATCH + bm * 128 + rl) * NP + gcol] =
                    f2h(acc[mi][ni][r]);
            }
        }
    }
}

// P partial-sum + blended bias + ELU + write next-layer aug (fp16, stride K2).
// One wave per row; 4 rows per block.
__global__ __launch_bounds__(256) void reduce_aug(
    const u16* __restrict__ P, const float* __restrict__ blend,
    const float* __restrict__ bias, u16* __restrict__ aug) {
    const int w = threadIdx.x >> 6, lane = threadIdx.x & 63;
    const int b = blockIdx.x * 4 + w;
    const int o0 = lane << 3;
    float v[8];
#pragma unroll
    for (int j = 0; j < 8; ++j) v[j] = 0.f;
#pragma unroll
    for (int s = 0; s < SPLIT; ++s) {
        const f16x8 a = *reinterpret_cast<const f16x8*>(
            P + ((size_t)s * BATCH + b) * 512 + o0);
#pragma unroll
        for (int j = 0; j < 8; ++j) v[j] += (float)a[j];
    }
    float bl[E_EXP];
#pragma unroll
    for (int e = 0; e < E_EXP; ++e) bl[e] = blend[e * BATCH + b];
#pragma unroll
    for (int e = 0; e < E_EXP; ++e) {
        const float* bp = bias + e * 512 + o0;
        float4 a = *reinterpret_cast<const float4*>(bp);
        float4 c = *reinterpret_cast<const float4*>(bp + 4);
        float s = bl[e];
        v[0] += s * a.x; v[1] += s * a.y; v[2] += s * a.z; v[3] += s * a.w;
        v[4] += s * c.x; v[5] += s * c.y; v[6] += s * c.z; v[7] += s * c.w;
    }
#pragma unroll
    for (int j = 0; j < 8; ++j) v[j] = v[j] > 0.f ? v[j] : expm1f(v[j]);
#pragma unroll
    for (int e = 0; e < E_EXP; ++e) {
        float s = bl[e];
        u16x8 o;
#pragma unroll
        for (int j = 0; j < 8; ++j) o[j] = f2h(s * v[j]);
        *reinterpret_cast<u16x8*>(aug + (size_t)b * K2 + e * 512 + o0) = o;
    }
}

// P partial-sum + blended bias + softmax -> out. 128 threads (2 waves) per row.
__global__ __launch_bounds__(128) void reduce_softmax(
    const u16* __restrict__ P, const float* __restrict__ blend,
    const float* __restrict__ bias, float* __restrict__ out) {
    const int b = blockIdx.x;
    const int tid = threadIdx.x, lane = tid & 63, w = tid >> 6;
    float bl[E_EXP];
#pragma unroll
    for (int e = 0; e < E_EXP; ++e) bl[e] = blend[e * BATCH + b];
    float v[3];
    int n = 0;
    float mx = -3.4e38f;
    for (int i = tid; i < D3; i += 128) {
        float s = 0.f;
#pragma unroll
        for (int sp = 0; sp < SPLIT; ++sp)
            s += (float)*reinterpret_cast<const _Float16*>(
                P + ((size_t)sp * BATCH + b) * N3PAD + i);
#pragma unroll
        for (int e = 0; e < E_EXP; ++e) s += bl[e] * bias[e * D3 + i];
        v[n] = s; mx = fmaxf(mx, s); ++n;
    }
#pragma unroll
    for (int off = 32; off >= 1; off >>= 1) mx = fmaxf(mx, __shfl_xor(mx, off, 64));
    __shared__ float sm[4];
    if (lane == 0) sm[w] = mx;
    __syncthreads();
    mx = fmaxf(sm[0], sm[1]);
    float s = 0.f;
    for (int j = 0; j < n; ++j) { v[j] = expf(v[j] - mx); s += v[j]; }
#pragma unroll
    for (int off = 32; off >= 1; off >>= 1) s += __shfl_xor(s, off, 64);
    if (lane == 0) sm[2 + w] = s;
    __syncthreads();
    float inv = 1.f / (sm[2] + sm[3]);
    n = 0;
    for (int i = tid; i < D3; i += 128) { out[(size_t)b * D3 + i] = v[n] * inv; ++n; }
}

extern "C" void kernel_launch(void* const* d_in, const int* in_sizes, int n_in,
                              void* d_out, int out_size, void* d_ws, size_t ws_size,
                              hipStream_t stream) {
    const float* x = (const float*)d_in[0];
    const float* blend = (const float*)d_in[1];
    const float* W1 = (const float*)d_in[2];
    const float* b1 = (const float*)d_in[3];
    const float* W2 = (const float*)d_in[4];
    const float* b2 = (const float*)d_in[5];
    const float* W3 = (const float*)d_in[6];
    const float* b3 = (const float*)d_in[7];
    float* outp = (float*)d_out;

    char* ws = (char*)d_ws;
    u16* wf1 = (u16*)ws;  ws += (size_t)512 * K1 * 2;        // 3.93 MB
    u16* wf2 = (u16*)ws;  ws += (size_t)512 * K2 * 2;        // 4.19 MB
    u16* wf3 = (u16*)ws;  ws += (size_t)N3PAD * K3 * 2;      // 3.15 MB
    u16* aug = (u16*)ws;  ws += (size_t)BATCH * K2 * 2;      // 67.1 MB
    u16* P = (u16*)ws;                                       // 2*8192*512*2 = 16.8 MB

    pack_all<<<1024, 256, 0, stream>>>(W1, W2, W3, wf1, wf2, wf3);
    build_aug<<<BATCH, 256, 0, stream>>>(x, blend, aug, D0, K1);
    gemm_splitk<<<64 * 4 * SPLIT, 512, 0, stream>>>(aug, wf1, P, K1, K1 / SPLIT, 512, 4);
    reduce_aug<<<BATCH / 4, 256, 0, stream>>>(P, blend, b1, aug);
    gemm_splitk<<<64 * 4 * SPLIT, 512, 0, stream>>>(aug, wf2, P, K2, K2 / SPLIT, 512, 4);
    reduce_aug<<<BATCH / 4, 256, 0, stream>>>(P, blend, b2, aug);
    gemm_splitk<<<64 * 3 * SPLIT, 512, 0, stream>>>(aug, wf3, P, K3, K3 / SPLIT, N3PAD, 3);
    reduce_softmax<<<BATCH, 128, 0, stream>>>(P, blend, b3, outp);
}